// Round 25
// baseline (72.223 us; speedup 1.0000x reference)
//
#include <hip/hip_runtime.h>
#include <hip/hip_bf16.h>

// Head attention: x[4,4096,1024] f32, Wq/Wk/Wv[1024,64] f32 -> out[4,4096,64] f32
// v25: proj8 = 8-row proj tiles, 16 KB LDS, grid 2048 -> 8 blocks/CU
//   (R5->v14 measured scaling: blocks/CU is the only lever that moved proj's
//   latency-bound chain; launch_bounds(256,8) caps VGPR at 64 which the
//   compiler already chooses, so nothing to sink). Rows 8-15 of each MFMA
//   are in-bounds duplicates (l15&7 clamp), discarded at the epilogue.
//   wtf/attnW byte-identical to v19 (best passing config).

#define BB 4
#define TT 4096
#define CC 1024
#define HH 64

typedef __attribute__((ext_vector_type(8))) short bf16x8;
typedef __attribute__((ext_vector_type(4))) float f32x4;

#if __has_builtin(__builtin_amdgcn_exp2f)
#define EXP2(x) __builtin_amdgcn_exp2f(x)
#else
#define EXP2(x) exp2f(x)
#endif

__device__ __forceinline__ short f2bf(float f) {
  union { float f; unsigned u; } v; v.f = f;
  unsigned r = v.u + 0x7fffu + ((v.u >> 16) & 1u);  // RNE
  return (short)(r >> 16);
}

__device__ __forceinline__ unsigned pk2bf(float lo, float hi) {  // packed RNE cvt
  __hip_bfloat162 p = __float22bfloat162_rn(make_float2(lo, hi));
  return *reinterpret_cast<unsigned*>(&p);
}

// ---------------- wtf: W -> WtF[nf 12][ks 32][lane 64][8] bf16 ---------------
// q part scaled by C^-0.5 * log2(e)  (softmax exp == exp2 of logits)
__global__ void wtf_kernel(const float* __restrict__ Wq, const float* __restrict__ Wk,
                           const float* __restrict__ Wv, short* __restrict__ WtF) {
  int idx = blockIdx.x * 256 + threadIdx.x;       // 24576
  int lane = idx & 63, ks = (idx >> 6) & 31, nf = idx >> 11;
  int l15 = lane & 15, lg = lane >> 4;
  int n = nf * 16 + l15;
  const float* W = (n < HH) ? Wq : ((n < 2 * HH) ? Wk : Wv);
  float sc = (n < HH) ? (0.03125f * 1.44269504f) : 1.0f;
  int k0 = ks * 32 + lg * 8, h = n & (HH - 1);
  bf16x8 r;
#pragma unroll
  for (int j = 0; j < 8; ++j) r[j] = f2bf(W[(k0 + j) * HH + h] * sc);
  *(bf16x8*)(WtF + (size_t)idx * 8) = r;
}

// ---------------- proj8: 8-row tiles, 16 KB LDS, 8 blocks/CU -----------------
// grid 2048, 256 thr (4 waves). Stage x[8][1024] f32->bf16 swizzled:
//   chunk c in [0,128), row r in [0,8):  S = (c*128 + r*16) ^ ((c&7)<<4).
// MFMA read: addr = ks*512 + lg*128 + (((l15&7)*16) ^ (((ks*4+lg)&7)<<4))
// (lanes l15>=8 duplicate rows 0-7 -> garbage acc rows, discarded).
// Epilogue: hb = (row0>>3)&1 half of the v17-verified (b,kt,cf) emission.
__launch_bounds__(256, 8)
__global__ void proj_kernel(const float* __restrict__ x, const short* __restrict__ WtF,
                            short* __restrict__ qo, short* __restrict__ kFo,
                            short* __restrict__ vFo) {
  __shared__ __align__(16) short xs[8192];        // 16 KB (stage + epilogue reuse)
  int t = threadIdx.x;
  int row0 = blockIdx.x * 8;
  int wave = t >> 6, lane = t & 63;
  int l15 = lane & 15, lg = lane >> 4;

  {  // ---- stage: thread (r = t>>5 in [0,8), kc = t&31), chunks kc + i*32 ----
    int r = t >> 5, kc = t & 31;
    const float4* xr4 = (const float4*)(x + (size_t)(row0 + r) * CC);
#pragma unroll
    for (int i = 0; i < 4; ++i) {
      int c = kc + i * 32;
      float4 a = xr4[c * 2], b2 = xr4[c * 2 + 1];
      uint4 w;
      w.x = pk2bf(a.x, a.y);   w.y = pk2bf(a.z, a.w);
      w.z = pk2bf(b2.x, b2.y); w.w = pk2bf(b2.z, b2.w);
      int S = (c * 128 + r * 16) ^ ((c & 7) << 4);
      *(uint4*)((char*)xs + S) = w;
    }
  }
  __syncthreads();

  int nf0 = wave * 3;
  const short* wp = WtF + ((size_t)nf0 * 32 * 64 + (size_t)lane) * 8;
  const char* xsb = (const char*)xs;
  int rl = (l15 & 7) * 16;                 // clamped row offset (in-bounds dup)

  f32x4 acc[3];
#pragma unroll
  for (int j = 0; j < 3; ++j) acc[j] = (f32x4){0.f, 0.f, 0.f, 0.f};

  bf16x8 wA[3], wB[3];
#pragma unroll
  for (int j = 0; j < 3; ++j) wA[j] = *(const bf16x8*)(wp + (size_t)j * 32 * 512);

#pragma unroll
  for (int ks = 0; ks < 32; ks += 2) {
#pragma unroll
    for (int j = 0; j < 3; ++j)
      wB[j] = *(const bf16x8*)(wp + ((size_t)j * 32 + ks + 1) * 512);
    bf16x8 a0 = *(const bf16x8*)(xsb + ks * 512 + lg * 128 +
                                 (rl ^ ((((ks * 4) + lg) & 7) << 4)));
#pragma unroll
    for (int j = 0; j < 3; ++j)
      acc[j] = __builtin_amdgcn_mfma_f32_16x16x32_bf16(a0, wA[j], acc[j], 0, 0, 0);
    if (ks + 2 < 32) {
#pragma unroll
      for (int j = 0; j < 3; ++j)
        wA[j] = *(const bf16x8*)(wp + ((size_t)j * 32 + ks + 2) * 512);
    }
    bf16x8 a1 = *(const bf16x8*)(xsb + (ks + 1) * 512 + lg * 128 +
                                 (rl ^ (((((ks + 1) * 4) + lg) & 7) << 4)));
#pragma unroll
    for (int j = 0; j < 3; ++j)
      acc[j] = __builtin_amdgcn_mfma_f32_16x16x32_bf16(a1, wB[j], acc[j], 0, 0, 0);
  }

  // ---- epilogue: valid acc rows are lg<2 (rows 0-7 of this 8-row tile) ----
  int b  = row0 >> 12;
  int kt = (row0 & 4095) >> 6;
  int cf = (row0 >> 4) & 3;
  int hb = (row0 >> 3) & 1;
  short* ksl = xs;           // k stage: [8 rows][72]
  short* vsl = xs + 1152;    // v stage: [64 h][24], local rows in slot 0

  __syncthreads();           // staged tile dead; reuse

  if (lg < 2) {
#pragma unroll
    for (int j = 0; j < 3; ++j) {
      int nf = nf0 + j;
      int h = (nf & 3) * 16 + l15;
      if (nf < 4) {            // q: row-major global (8 rows)
#pragma unroll
        for (int reg = 0; reg < 4; ++reg)
          qo[(size_t)(row0 + lg * 4 + reg) * HH + h] = f2bf(acc[j][reg]);
      } else if (nf < 8) {     // k: stage [local row][h], stride 72
#pragma unroll
        for (int reg = 0; reg < 4; ++reg)
          ksl[(lg * 4 + reg) * 72 + h] = f2bf(acc[j][reg]);
      } else {                 // v: stage transposed [h][local row], packed
        uint2 w2;
        w2.x = pk2bf(acc[j][0], acc[j][1]);
        w2.y = pk2bf(acc[j][2], acc[j][3]);
        *(uint2*)(vsl + h * 24 + lg * 4) = w2;
      }
    }
  }
  __syncthreads();

  size_t tileoff = ((size_t)b * 64 + kt) * 4096;
  if (t < 128) {             // kF chunks ld = cf*2 + ks2; lanes with l15o half hb
    int ks2 = t >> 6, ln = t & 63;
    int l15o = ln & 15, lgo = ln >> 4;
    if ((l15o >> 3) == hb) {
      bf16x8 r = *(const bf16x8*)(ksl + (l15o & 7) * 72 + ks2 * 32 + lgo * 8);
      *(bf16x8*)(kFo + tileoff + (size_t)(cf * 2 + ks2) * 512 + ln * 8) = r;
    }
  } else if (t < 256) {      // vF chunks ld = hf*2 + (cf>>1); lane group = 2(cf&1)+hb
    int t2 = t - 128;
    int hf = t2 >> 5, lgl = (t2 >> 4) & 1, l15o = t2 & 15;
    if (lgl == hb) {
      bf16x8 r = *(const bf16x8*)(vsl + (hf * 16 + l15o) * 24);
      int lnout = (2 * (cf & 1) + hb) * 16 + l15o;
      *(bf16x8*)(vFo + tileoff + (size_t)(hf * 2 + (cf >> 1)) * 512 + lnout * 8) = r;
    }
  }
}

// ---------------- attnW: swapped QK^T + packed P writes ----------------------
// (byte-identical to v15/v16/v17/v19)
__launch_bounds__(512, 4)
__global__ void attnW_kernel(const short* __restrict__ q, const short* __restrict__ kF,
                             const short* __restrict__ vF, float* __restrict__ out) {
  __shared__ __align__(16) short ps[8][2560];
  __shared__ __align__(16) float macc[32][68];
  __shared__ float lL[32];
  int wave = threadIdx.x >> 6, lane = threadIdx.x & 63;
  int l15 = lane & 15, lg = lane >> 4;
  int low3 = blockIdx.x & 7;                 // XCD id (perf heuristic only)
  int b  = low3 >> 1;                        // 2 XCDs per batch -> L2-resident KV
  int qt = ((blockIdx.x >> 3) << 1) | (low3 & 1);   // 0..127
  int brow0 = qt * 32;

  const short* qb = q + ((size_t)b * TT + brow0 + l15) * HH;
  bf16x8 qa[2][2];
#pragma unroll
  for (int g = 0; g < 2; ++g) {
    qa[g][0] = *(const bf16x8*)(qb + g * 16 * HH + lg * 8);
    qa[g][1] = *(const bf16x8*)(qb + g * 16 * HH + 32 + lg * 8);
  }

  bf16x8 ones;
#pragma unroll
  for (int j = 0; j < 8; ++j) ones[j] = (short)0x3F80;   // bf16 1.0

  const short* kfb = kF + (size_t)b * 262144 + (size_t)lane * 8;
  const short* vfb = vF + (size_t)b * 262144 + (size_t)lane * 8;

  f32x4 acc[2][4], accl[2];
#pragma unroll
  for (int g = 0; g < 2; ++g) {
#pragma unroll
    for (int i = 0; i < 4; ++i) acc[g][i] = (f32x4){0.f, 0.f, 0.f, 0.f};
    accl[g] = (f32x4){0.f, 0.f, 0.f, 0.f};
  }

  char* psw = (char*)&ps[wave][0];
  int xorv = (l15 >> 3) << 4;
  int pwbase = l15 * 80;                       // write row = l15 (qrow)
  int pr = l15 * 80 + ((lg << 4) ^ xorv);      // read: row=l15, colbytes lg*16..

  for (int t = wave * 16; t < wave * 16 + 16; ++t) {
    const short* kp = kfb + (size_t)t * 2048;
    const short* vp = vfb + (size_t)(t >> 1) * 4096 + (size_t)(t & 1) * 512;
    bf16x8 kf[4], vf[4];
#pragma unroll
    for (int ld = 0; ld < 4; ++ld) kf[ld] = *(const bf16x8*)(kp + ld * 512);
#pragma unroll
    for (int hf = 0; hf < 4; ++hf) vf[hf] = *(const bf16x8*)(vp + hf * 1024);
#pragma unroll
    for (int g = 0; g < 2; ++g)
#pragma unroll
      for (int cf = 0; cf < 2; ++cf) {
        f32x4 t4 = (f32x4){0.f, 0.f, 0.f, 0.f};
        t4 = __builtin_amdgcn_mfma_f32_16x16x32_bf16(kf[cf * 2], qa[g][0], t4, 0, 0, 0);
        t4 = __builtin_amdgcn_mfma_f32_16x16x32_bf16(kf[cf * 2 + 1], qa[g][1], t4, 0, 0, 0);
        float p0 = EXP2(t4[0]), p1 = EXP2(t4[1]);
        float p2 = EXP2(t4[2]), p3 = EXP2(t4[3]);
        unsigned w01 = pk2bf(p0, p1);
        unsigned w23 = pk2bf(p2, p3);
        int cb = (cf << 5) + (lg << 3);        // column byte = kv*2
        *(unsigned*)(psw + g * 1280 + pwbase + ((cb) ^ xorv)) = w01;
        *(unsigned*)(psw + g * 1280 + pwbase + ((cb + 4) ^ xorv)) = w23;
      }
    bf16x8 pa0 = *(const bf16x8*)(psw + pr);
    bf16x8 pa1 = *(const bf16x8*)(psw + 1280 + pr);
    __builtin_amdgcn_s_setprio(1);
#pragma unroll
    for (int hf = 0; hf < 4; ++hf) {
      acc[0][hf] = __builtin_amdgcn_mfma_f32_16x16x32_bf16(pa0, vf[hf], acc[0][hf], 0, 0, 0);
      acc[1][hf] = __builtin_amdgcn_mfma_f32_16x16x32_bf16(pa1, vf[hf], acc[1][hf], 0, 0, 0);
    }
    accl[0] = __builtin_amdgcn_mfma_f32_16x16x32_bf16(pa0, ones, accl[0], 0, 0, 0);
    accl[1] = __builtin_amdgcn_mfma_f32_16x16x32_bf16(pa1, ones, accl[1], 0, 0, 0);
    __builtin_amdgcn_s_setprio(0);
  }

#pragma unroll
  for (int ph = 0; ph < 8; ++ph) {
    if (wave == ph) {
#pragma unroll
      for (int g = 0; g < 2; ++g)
#pragma unroll
        for (int reg = 0; reg < 4; ++reg) {
          int row = g * 16 + lg * 4 + reg;
          if (ph == 0) {
#pragma unroll
            for (int hf = 0; hf < 4; ++hf)
              macc[row][hf * 16 + l15] = acc[g][hf][reg];
            if (l15 == 0) lL[row] = accl[g][reg];
          } else {
#pragma unroll
            for (int hf = 0; hf < 4; ++hf)
              macc[row][hf * 16 + l15] += acc[g][hf][reg];
            if (l15 == 0) lL[row] += accl[g][reg];
          }
        }
    }
    __syncthreads();
  }

  {
    int tt = threadIdx.x;
    int r = tt >> 4, c0 = (tt & 15) * 4;
    float linv = 1.0f / lL[r];
    float4 o;
    o.x = macc[r][c0 + 0] * linv; o.y = macc[r][c0 + 1] * linv;
    o.z = macc[r][c0 + 2] * linv; o.w = macc[r][c0 + 3] * linv;
    *(float4*)(out + ((size_t)b * TT + brow0 + r) * HH + c0) = o;
  }
}

extern "C" void kernel_launch(void* const* d_in, const int* in_sizes, int n_in,
                              void* d_out, int out_size, void* d_ws, size_t ws_size,
                              hipStream_t stream) {
  const float* x  = (const float*)d_in[0];
  const float* Wq = (const float*)d_in[1];
  const float* Wk = (const float*)d_in[2];
  const float* Wv = (const float*)d_in[3];
  float* out = (float*)d_out;

  char* ws = (char*)d_ws;
  short* WtF = (short*)ws;                 // 384 KB (pad to 512K)
  short* q   = (short*)(ws + 0x080000);    // 2 MB
  short* kF  = (short*)(ws + 0x280000);    // 2 MB
  short* vF  = (short*)(ws + 0x480000);    // 2 MB -> 6.5 MB total

  hipLaunchKernelGGL(wtf_kernel,   dim3(96),   dim3(256), 0, stream, Wq, Wk, Wv, WtF);
  hipLaunchKernelGGL(proj_kernel,  dim3(2048), dim3(256), 0, stream, x, WtF, q, kF, vF);
  hipLaunchKernelGGL(attnW_kernel, dim3(512),  dim3(512), 0, stream, q, kF, vF, out);
}

// Round 27
// 65.500 us; speedup vs baseline: 1.1026x; 1.1026x over previous
//
#include <hip/hip_runtime.h>
#include <hip/hip_bf16.h>

// Head attention: x[4,4096,1024] f32, Wq/Wk/Wv[1024,64] f32 -> out[4,4096,64] f32
// v27 = v26 with 4 rolling W buffers (v26's 3-buf scheme wrote the buffer
//   being read in the same iteration -> rare DS-queue-vs-DMA race, 9.9e-3).
//   4 bufs: write target (ks+3)%4 != read ks%4; last reader was iter ks-1,
//   lgkmcnt-retired before this iter's WAITVM -> strictly ordered. 80 KB LDS
//   = exactly 2 blocks/CU. vmcnt counts unchanged (distance still 3).
//   wtf/attnW byte-identical to v19.

#define BB 4
#define TT 4096
#define CC 1024
#define HH 64

typedef __attribute__((ext_vector_type(8))) short bf16x8;
typedef __attribute__((ext_vector_type(4))) float f32x4;

#if __has_builtin(__builtin_amdgcn_exp2f)
#define EXP2(x) __builtin_amdgcn_exp2f(x)
#else
#define EXP2(x) exp2f(x)
#endif

__device__ __forceinline__ short f2bf(float f) {
  union { float f; unsigned u; } v; v.f = f;
  unsigned r = v.u + 0x7fffu + ((v.u >> 16) & 1u);  // RNE
  return (short)(r >> 16);
}

__device__ __forceinline__ unsigned pk2bf(float lo, float hi) {  // packed RNE cvt
  __hip_bfloat162 p = __float22bfloat162_rn(make_float2(lo, hi));
  return *reinterpret_cast<unsigned*>(&p);
}

__device__ __forceinline__ void gload16(const short* g, short* l) {
  __builtin_amdgcn_global_load_lds(
      (const __attribute__((address_space(1))) void*)g,
      (__attribute__((address_space(3))) void*)l, 16, 0, 0);
}

#define WAITVM(N) asm volatile("s_waitcnt vmcnt(" #N ")" ::: "memory")

// ---------------- wtf: W -> WtF[nf 12][ks 32][lane 64][8] bf16 ---------------
// q part scaled by C^-0.5 * log2(e)  (softmax exp == exp2 of logits)
__global__ void wtf_kernel(const float* __restrict__ Wq, const float* __restrict__ Wk,
                           const float* __restrict__ Wv, short* __restrict__ WtF) {
  int idx = blockIdx.x * 256 + threadIdx.x;       // 24576
  int lane = idx & 63, ks = (idx >> 6) & 31, nf = idx >> 11;
  int l15 = lane & 15, lg = lane >> 4;
  int n = nf * 16 + l15;
  const float* W = (n < HH) ? Wq : ((n < 2 * HH) ? Wk : Wv);
  float sc = (n < HH) ? (0.03125f * 1.44269504f) : 1.0f;
  int k0 = ks * 32 + lg * 8, h = n & (HH - 1);
  bf16x8 r;
#pragma unroll
  for (int j = 0; j < 8; ++j) r[j] = f2bf(W[(k0 + j) * HH + h] * sc);
  *(bf16x8*)(WtF + (size_t)idx * 8) = r;
}

// ---------------- projP: rolling-DMA WtF pipeline proj (4 buffers) -----------
// grid 1024 (16-row tiles), 256 thr (4 waves), 80 KB LDS -> 2 blocks/CU.
// Wave's W slab: wlds[buf 4][wave 4][j 3][512 shorts] (1 KB chunks).
// Iter ks: WAITVM(ks<=29 ? 6 : ks==30 ? 3 : 0)  [exact: retired = 3(ks+1)]
//   -> ds_read w0..w2 + swizzled a-frag -> 3 MFMA -> issue DMA(ks+3) into
//   buf (ks+3)%4 (!= read buf ks%4; race-free by iter-(ks-1) retirement).
__launch_bounds__(256, 2)
__global__ void projP_kernel(const float* __restrict__ x, const short* __restrict__ WtF,
                             short* __restrict__ qo, short* __restrict__ kFo,
                             short* __restrict__ vFo) {
  __shared__ __align__(16) short xs[16384];       // 32 KB x tile (+ epilogue reuse)
  __shared__ __align__(16) short wlds[24576];     // 48 KB W rolling buffers (4)
  int t = threadIdx.x;
  int row0 = blockIdx.x * 16;
  int wave = t >> 6, lane = t & 63;
  int l15 = lane & 15, lg = lane >> 4;

  {  // ---- stage x[16][1024] f32 -> bf16 frag-order LDS, XOR-swizzled ----
    int r = t >> 4, kc = t & 15;
    const float4* xr4 = (const float4*)(x + (size_t)(row0 + r) * CC) + kc * 2;
#pragma unroll
    for (int i = 0; i < 8; ++i) {
      float4 a = xr4[i * 32], b2 = xr4[i * 32 + 1];
      uint4 w;
      w.x = pk2bf(a.x, a.y);   w.y = pk2bf(a.z, a.w);
      w.z = pk2bf(b2.x, b2.y); w.w = pk2bf(b2.z, b2.w);
      int c = kc + i * 16;
      int S = (c * 256 + r * 16) ^ ((c & 7) << 4);
      *(uint4*)((char*)xs + S) = w;
    }
  }
  __syncthreads();

  int nf0 = wave * 3;
  const short* wp = WtF + ((size_t)nf0 * 32 * 64 + (size_t)lane) * 8;
  short* wbase = wlds + wave * 1536;   // + buf*6144 + j*512

  // prologue: DMA ks = 0,1,2 into bufs 0,1,2 (9 loads in flight; buf 3 empty)
#pragma unroll
  for (int kp = 0; kp < 3; ++kp)
#pragma unroll
    for (int j = 0; j < 3; ++j)
      gload16(wp + ((size_t)j * 32 + kp) * 512, wbase + kp * 6144 + j * 512);

  f32x4 acc[3];
#pragma unroll
  for (int j = 0; j < 3; ++j) acc[j] = (f32x4){0.f, 0.f, 0.f, 0.f};
  const char* xsb = (const char*)xs;

#pragma unroll
  for (int ks = 0; ks < 32; ++ks) {
    if (ks <= 29)      { WAITVM(6); }
    else if (ks == 30) { WAITVM(3); }
    else               { WAITVM(0); }
    const short* wb = wbase + (ks % 4) * 6144;
    bf16x8 w0 = *(const bf16x8*)(wb + 0 * 512 + lane * 8);
    bf16x8 w1 = *(const bf16x8*)(wb + 1 * 512 + lane * 8);
    bf16x8 w2 = *(const bf16x8*)(wb + 2 * 512 + lane * 8);
    bf16x8 a = *(const bf16x8*)(xsb + ks * 1024 +
                  ((lane * 16) ^ ((((ks * 4) + lg) & 7) << 4)));
    acc[0] = __builtin_amdgcn_mfma_f32_16x16x32_bf16(a, w0, acc[0], 0, 0, 0);
    acc[1] = __builtin_amdgcn_mfma_f32_16x16x32_bf16(a, w1, acc[1], 0, 0, 0);
    acc[2] = __builtin_amdgcn_mfma_f32_16x16x32_bf16(a, w2, acc[2], 0, 0, 0);
    if (ks + 3 < 32) {
#pragma unroll
      for (int j = 0; j < 3; ++j)
        gload16(wp + ((size_t)j * 32 + ks + 3) * 512,
                wbase + ((ks + 3) % 4) * 6144 + j * 512);
    }
  }

  // ---- epilogue (v17-verified): q row-major; k/v via LDS -> kF/vF ----
  int b  = row0 >> 12;
  int kt = (row0 & 4095) >> 6;
  int cf = (row0 >> 4) & 3;
  short* ksl = xs;           // k stage: [16 rows][72]  (144B rows)
  short* vsl = xs + 1152;    // v stage: [64 h][24]

  __syncthreads();           // staged tile dead; reuse

#pragma unroll
  for (int j = 0; j < 3; ++j) {
    int nf = nf0 + j;
    int h = (nf & 3) * 16 + l15;
    if (nf < 4) {            // q: row-major global
#pragma unroll
      for (int reg = 0; reg < 4; ++reg)
        qo[(size_t)(row0 + lg * 4 + reg) * HH + h] = f2bf(acc[j][reg]);
    } else if (nf < 8) {     // k: stage [row][h], stride 72
#pragma unroll
      for (int reg = 0; reg < 4; ++reg)
        ksl[(lg * 4 + reg) * 72 + h] = f2bf(acc[j][reg]);
    } else {                 // v: stage transposed [h][row], packed
      uint2 w2;
      w2.x = pk2bf(acc[j][0], acc[j][1]);
      w2.y = pk2bf(acc[j][2], acc[j][3]);
      *(uint2*)(vsl + h * 24 + lg * 4) = w2;
    }
  }
  __syncthreads();

  size_t tileoff = ((size_t)b * 64 + kt) * 4096;
  if (t < 128) {             // kF chunks ld = cf*2 + ks2 (full)
    int ks2 = t >> 6, ln = t & 63;
    int l15o = ln & 15, lgo = ln >> 4;
    bf16x8 r = *(const bf16x8*)(ksl + l15o * 72 + ks2 * 32 + lgo * 8);
    *(bf16x8*)(kFo + tileoff + (size_t)(cf * 2 + ks2) * 512 + ln * 8) = r;
  } else if (t < 256) {      // vF chunks ld = hf*2 + (cf>>1), lanes lg-subset
    int t2 = t - 128;
    int hf = t2 >> 5, lgl = (t2 >> 4) & 1, l15o = t2 & 15;
    bf16x8 r = *(const bf16x8*)(vsl + (hf * 16 + l15o) * 24 + lgl * 8);
    int lnout = (2 * (cf & 1) + lgl) * 16 + l15o;
    *(bf16x8*)(vFo + tileoff + (size_t)(hf * 2 + (cf >> 1)) * 512 + lnout * 8) = r;
  }
}

// ---------------- attnW: swapped QK^T + packed P writes ----------------------
// (byte-identical to v15/v16/v17/v19)
__launch_bounds__(512, 4)
__global__ void attnW_kernel(const short* __restrict__ q, const short* __restrict__ kF,
                             const short* __restrict__ vF, float* __restrict__ out) {
  __shared__ __align__(16) short ps[8][2560];
  __shared__ __align__(16) float macc[32][68];
  __shared__ float lL[32];
  int wave = threadIdx.x >> 6, lane = threadIdx.x & 63;
  int l15 = lane & 15, lg = lane >> 4;
  int low3 = blockIdx.x & 7;                 // XCD id (perf heuristic only)
  int b  = low3 >> 1;                        // 2 XCDs per batch -> L2-resident KV
  int qt = ((blockIdx.x >> 3) << 1) | (low3 & 1);   // 0..127
  int brow0 = qt * 32;

  const short* qb = q + ((size_t)b * TT + brow0 + l15) * HH;
  bf16x8 qa[2][2];
#pragma unroll
  for (int g = 0; g < 2; ++g) {
    qa[g][0] = *(const bf16x8*)(qb + g * 16 * HH + lg * 8);
    qa[g][1] = *(const bf16x8*)(qb + g * 16 * HH + 32 + lg * 8);
  }

  bf16x8 ones;
#pragma unroll
  for (int j = 0; j < 8; ++j) ones[j] = (short)0x3F80;   // bf16 1.0

  const short* kfb = kF + (size_t)b * 262144 + (size_t)lane * 8;
  const short* vfb = vF + (size_t)b * 262144 + (size_t)lane * 8;

  f32x4 acc[2][4], accl[2];
#pragma unroll
  for (int g = 0; g < 2; ++g) {
#pragma unroll
    for (int i = 0; i < 4; ++i) acc[g][i] = (f32x4){0.f, 0.f, 0.f, 0.f};
    accl[g] = (f32x4){0.f, 0.f, 0.f, 0.f};
  }

  char* psw = (char*)&ps[wave][0];
  int xorv = (l15 >> 3) << 4;
  int pwbase = l15 * 80;                       // write row = l15 (qrow)
  int pr = l15 * 80 + ((lg << 4) ^ xorv);      // read: row=l15, colbytes lg*16..

  for (int t = wave * 16; t < wave * 16 + 16; ++t) {
    const short* kp = kfb + (size_t)t * 2048;
    const short* vp = vfb + (size_t)(t >> 1) * 4096 + (size_t)(t & 1) * 512;
    bf16x8 kf[4], vf[4];
#pragma unroll
    for (int ld = 0; ld < 4; ++ld) kf[ld] = *(const bf16x8*)(kp + ld * 512);
#pragma unroll
    for (int hf = 0; hf < 4; ++hf) vf[hf] = *(const bf16x8*)(vp + hf * 1024);
#pragma unroll
    for (int g = 0; g < 2; ++g)
#pragma unroll
      for (int cf = 0; cf < 2; ++cf) {
        f32x4 t4 = (f32x4){0.f, 0.f, 0.f, 0.f};
        t4 = __builtin_amdgcn_mfma_f32_16x16x32_bf16(kf[cf * 2], qa[g][0], t4, 0, 0, 0);
        t4 = __builtin_amdgcn_mfma_f32_16x16x32_bf16(kf[cf * 2 + 1], qa[g][1], t4, 0, 0, 0);
        float p0 = EXP2(t4[0]), p1 = EXP2(t4[1]);
        float p2 = EXP2(t4[2]), p3 = EXP2(t4[3]);
        unsigned w01 = pk2bf(p0, p1);
        unsigned w23 = pk2bf(p2, p3);
        int cb = (cf << 5) + (lg << 3);        // column byte = kv*2
        *(unsigned*)(psw + g * 1280 + pwbase + ((cb) ^ xorv)) = w01;
        *(unsigned*)(psw + g * 1280 + pwbase + ((cb + 4) ^ xorv)) = w23;
      }
    bf16x8 pa0 = *(const bf16x8*)(psw + pr);
    bf16x8 pa1 = *(const bf16x8*)(psw + 1280 + pr);
    __builtin_amdgcn_s_setprio(1);
#pragma unroll
    for (int hf = 0; hf < 4; ++hf) {
      acc[0][hf] = __builtin_amdgcn_mfma_f32_16x16x32_bf16(pa0, vf[hf], acc[0][hf], 0, 0, 0);
      acc[1][hf] = __builtin_amdgcn_mfma_f32_16x16x32_bf16(pa1, vf[hf], acc[1][hf], 0, 0, 0);
    }
    accl[0] = __builtin_amdgcn_mfma_f32_16x16x32_bf16(pa0, ones, accl[0], 0, 0, 0);
    accl[1] = __builtin_amdgcn_mfma_f32_16x16x32_bf16(pa1, ones, accl[1], 0, 0, 0);
    __builtin_amdgcn_s_setprio(0);
  }

#pragma unroll
  for (int ph = 0; ph < 8; ++ph) {
    if (wave == ph) {
#pragma unroll
      for (int g = 0; g < 2; ++g)
#pragma unroll
        for (int reg = 0; reg < 4; ++reg) {
          int row = g * 16 + lg * 4 + reg;
          if (ph == 0) {
#pragma unroll
            for (int hf = 0; hf < 4; ++hf)
              macc[row][hf * 16 + l15] = acc[g][hf][reg];
            if (l15 == 0) lL[row] = accl[g][reg];
          } else {
#pragma unroll
            for (int hf = 0; hf < 4; ++hf)
              macc[row][hf * 16 + l15] += acc[g][hf][reg];
            if (l15 == 0) lL[row] += accl[g][reg];
          }
        }
    }
    __syncthreads();
  }

  {
    int tt = threadIdx.x;
    int r = tt >> 4, c0 = (tt & 15) * 4;
    float linv = 1.0f / lL[r];
    float4 o;
    o.x = macc[r][c0 + 0] * linv; o.y = macc[r][c0 + 1] * linv;
    o.z = macc[r][c0 + 2] * linv; o.w = macc[r][c0 + 3] * linv;
    *(float4*)(out + ((size_t)b * TT + brow0 + r) * HH + c0) = o;
  }
}

extern "C" void kernel_launch(void* const* d_in, const int* in_sizes, int n_in,
                              void* d_out, int out_size, void* d_ws, size_t ws_size,
                              hipStream_t stream) {
  const float* x  = (const float*)d_in[0];
  const float* Wq = (const float*)d_in[1];
  const float* Wk = (const float*)d_in[2];
  const float* Wv = (const float*)d_in[3];
  float* out = (float*)d_out;

  char* ws = (char*)d_ws;
  short* WtF = (short*)ws;                 // 384 KB (pad to 512K)
  short* q   = (short*)(ws + 0x080000);    // 2 MB
  short* kF  = (short*)(ws + 0x280000);    // 2 MB
  short* vF  = (short*)(ws + 0x480000);    // 2 MB -> 6.5 MB total

  hipLaunchKernelGGL(wtf_kernel,   dim3(96),   dim3(256), 0, stream, Wq, Wk, Wv, WtF);
  hipLaunchKernelGGL(projP_kernel, dim3(1024), dim3(256), 0, stream, x, WtF, q, kF, vF);
  hipLaunchKernelGGL(attnW_kernel, dim3(512),  dim3(512), 0, stream, q, kF, vF, out);
}